// Round 4
// baseline (66.920 us; speedup 1.0000x reference)
//
#include <hip/hip_runtime.h>
#include <hip/hip_bf16.h>

typedef __attribute__((ext_vector_type(8))) short short8;
typedef __attribute__((ext_vector_type(8))) unsigned short u16x8;
typedef __attribute__((ext_vector_type(4))) float f32x4;

constexpr int NB = 64;     // batch
constexpr int NL = 96;     // time / conv channels
constexpr int NC = 2048;   // feature / conv spatial
constexpr int TT = 64;     // conv spatial tile per block
constexpr int KTOT = 288;  // GEMM K = 96 ch * 3 taps, k = tau*96 + i
constexpr int LROW = 104;  // LDS row pitch (bf16 elems), rows 16B-aligned
constexpr float LOG2E = 1.44269504088896340736f;

__device__ inline unsigned short f2bf(float f) {
    union { float f; unsigned u; } v; v.f = f;
    unsigned r = v.u + 0x7fff + ((v.u >> 16) & 1);   // RNE
    return (unsigned short)(r >> 16);
}

// packed f32x2 -> bf16x2 (RNE), single instruction
__device__ inline unsigned cvt_pk_bf16(float lo, float hi) {
    unsigned r;
    asm("v_cvt_pk_bf16_f32 %0, %1, %2" : "=v"(r) : "v"(lo), "v"(hi));
    return r;
}

// ---------------------------------------------------------------------------
// Weight permute+convert: Aw[o][k], k = tau*96 + i, bf16.
// ---------------------------------------------------------------------------
__global__ void prep_aw(const float* __restrict__ w, unsigned short* __restrict__ aw)
{
    int idx = blockIdx.x * 256 + threadIdx.x;
    if (idx >= NL * KTOT) return;
    int o = idx / KTOT, k = idx - o * KTOT;
    int tau = k / NL, i = k - tau * NL;
    aw[idx] = f2bf(w[(o * NL + i) * 3 + tau]);
}

// ---------------------------------------------------------------------------
// Decomp for one (column c, l-chunk Q*32..Q*32+31). Reads bf16 x from the
// staged LDS tile (b128, unpack = shift/and), in-register cumsum (static
// indices), means + softmax gate (exp2, pre-scaled weights, no max-sub),
// writes ONLY mm (bf16 via cvt_pk) into the second LDS buffer.
// ---------------------------------------------------------------------------
template<int Q>
__device__ __forceinline__ void decomp_chunk(
    int c, float w0, float w1, float w2, float b0, float b1, float b2,
    unsigned short (*sbuf)[TT + 2][LROW])   // [0]=x tile, [1]=mm tile
{
    constexpr int R0 = (Q == 0) ? 0 : 32 * Q - 12;
    constexpr int R1 = (Q == 2) ? 95 : 32 * Q + 43;
    constexpr int O0 = R0 / 8;
    constexpr int O1 = R1 / 8;
    constexpr int NR = R1 - R0 + 1;        // 44 / 56 / 44

    float lcs[NR + 1];
    lcs[0] = 0.0f;
#pragma unroll
    for (int oc = O0; oc <= O1; ++oc) {
        union { u16x8 v; unsigned d[4]; } u;
        u.v = *(const u16x8*)(&sbuf[0][c][oc * 8]);
#pragma unroll
        for (int h = 0; h < 4; ++h) {
            const int r = oc * 8 + 2 * h;
            float flo = __uint_as_float(u.d[h] << 16);
            float fhi = __uint_as_float(u.d[h] & 0xffff0000u);
            if (r >= R0 && r <= R1)         lcs[r - R0 + 1] = lcs[r - R0] + flo;
            if (r + 1 >= R0 && r + 1 <= R1) lcs[r - R0 + 2] = lcs[r - R0 + 1] + fhi;
        }
    }
    float xf = lcs[1];                 // x[0]  (valid when Q==0)
    float xe = lcs[NR] - lcs[NR - 1];  // x[95] (valid when Q==2)

    unsigned md[16];
    float pmm = 0.0f;
#pragma unroll
    for (int j = 0; j < 32; ++j) {
        const int l = 32 * Q + j;
        float xl = lcs[l - R0 + 1] - lcs[l - R0];
        float m5, m13, m25;
#define MEANK(P, K, DST) do { \
        int lo = l - (P), hi = l + (P); \
        int loc = (lo < 0 ? 0 : lo) - R0, hic = (hi > 95 ? 95 : hi) - R0; \
        float s = lcs[hic + 1] - lcs[loc]; \
        if (lo < 0) s += (float)(-lo) * xf; \
        if (hi > 95) s += (float)(hi - 95) * xe; \
        DST = s * (1.0f / (K)); } while (0)
        MEANK(2, 5, m5);
        MEANK(6, 13, m13);
        MEANK(12, 25, m25);
#undef MEANK
        // softmax over 3 logits; |logit| small enough to skip max-sub.
        float e0 = exp2f(fmaf(xl, w0, b0));
        float e1 = exp2f(fmaf(xl, w1, b1));
        float e2 = exp2f(fmaf(xl, w2, b2));
        float inv = 1.0f / (e0 + e1 + e2);
        float mmv = fmaf(m5, e0, fmaf(m13, e1, m25 * e2)) * inv;
        if ((j & 1) == 0) pmm = mmv;
        else              md[j >> 1] = cvt_pk_bf16(pmm, mmv);
    }
#pragma unroll
    for (int v = 0; v < 4; ++v) {
        union { u16x8 vv; unsigned d[4]; } o;
        o.d[0] = md[v*4]; o.d[1] = md[v*4+1]; o.d[2] = md[v*4+2]; o.d[3] = md[v*4+3];
        *(u16x8*)(&sbuf[1][c][32 * Q + v * 8]) = o.vv;
    }
}

// ---------------------------------------------------------------------------
// Fused kernel, block = (batch b, 64-wide spatial tile):
//   Phase 0: all 256 threads stage x-tile -> bf16 LDS (GEMM-B layout).
//   Phase 1: 198 units (66 cols x 3 l-chunks) compute mm -> LDS.
//   Phase 2: conv is linear: out1 = C(mm), out0 = C(x) - C(mm) as one
//            bf16 MFMA GEMM pass over both B-tiles (x and mm).
// ---------------------------------------------------------------------------
__global__ __launch_bounds__(256, 4) void fused_kernel(
    const float* __restrict__ x,
    const float* __restrict__ gw,
    const float* __restrict__ gb,
    const unsigned short* __restrict__ aw,
    float* __restrict__ out0,
    float* __restrict__ out1)
{
    __shared__ unsigned short sbuf[2][TT + 2][LROW];   // [0]=x, [1]=mm

    int b = blockIdx.x;
    int t0 = blockIdx.y * TT;
    size_t xb = (size_t)b * NL * NC;

    int lane = threadIdx.x & 63;
    int wv = threadIdx.x >> 6;
    int mg = wv & 1, ng = wv >> 1;
    int lr = lane & 15, lk = lane >> 4;

    // ---- Phase 0: stage x -> bf16 LDS tile (792 units of 8 rows x 1 col) ----
    for (int u = threadIdx.x; u < (TT + 2) * 12; u += 256) {
        int o = u / (TT + 2), c = u - o * (TT + 2);
        int t = (t0 - 1 + c) & (NC - 1);               // circular halo
        const float* xp = x + xb + (size_t)(o * 8) * NC + t;
        union { u16x8 v; unsigned d[4]; } pk;
#pragma unroll
        for (int h = 0; h < 4; ++h)
            pk.d[h] = cvt_pk_bf16(xp[(size_t)(2 * h) * NC], xp[(size_t)(2 * h + 1) * NC]);
        *(u16x8*)(&sbuf[0][c][o * 8]) = pk.v;
    }
    __syncthreads();

    // ---- Phase 1: decomposition -> mm tile ----
    if (threadIdx.x < 198) {
        float w0 = gw[0] * LOG2E, w1 = gw[1] * LOG2E, w2 = gw[2] * LOG2E;
        float b0 = gb[0] * LOG2E, b1 = gb[1] * LOG2E, b2 = gb[2] * LOG2E;
        int q = threadIdx.x / 66;
        int c = threadIdx.x - q * 66;
        if (q == 0)      decomp_chunk<0>(c, w0, w1, w2, b0, b1, b2, sbuf);
        else if (q == 1) decomp_chunk<1>(c, w0, w1, w2, b0, b1, b2, sbuf);
        else             decomp_chunk<2>(c, w0, w1, w2, b0, b1, b2, sbuf);
    }

    // A-fragment load (L2-hot 55 KB) — issued before the barrier wait
    const unsigned short* abase = aw + (size_t)(mg * 48 + lr) * KTOT + lk * 8;
    short8 aCur[3], aNxt[3];
#pragma unroll
    for (int mt = 0; mt < 3; ++mt)
        aCur[mt] = *(const short8*)(abase + mt * 16 * KTOT);

    __syncthreads();

    // ---- Phase 2: MFMA GEMM over both B-tiles ----
    f32x4 acc[3][2][2] = {};

#pragma unroll
    for (int ks = 0; ks < 9; ++ks) {
        if (ks < 8) {
#pragma unroll
            for (int mt = 0; mt < 3; ++mt)
                aNxt[mt] = *(const short8*)(abase + mt * 16 * KTOT + (ks + 1) * 32);
        }
        const int tau = ks / 3;
        const int i0 = (ks - tau * 3) * 32;
        short8 bf[2][2];
#pragma unroll
        for (int nt = 0; nt < 2; ++nt) {
            int r = ng * 32 + nt * 16 + lr + tau;   // LDS row = local t + tau
#pragma unroll
            for (int sig = 0; sig < 2; ++sig)
                bf[nt][sig] = *(const short8*)(&sbuf[sig][r][i0 + lk * 8]);
        }
#pragma unroll
        for (int mt = 0; mt < 3; ++mt)
#pragma unroll
            for (int nt = 0; nt < 2; ++nt)
#pragma unroll
                for (int sig = 0; sig < 2; ++sig)
                    acc[mt][nt][sig] = __builtin_amdgcn_mfma_f32_16x16x32_bf16(
                        aCur[mt], bf[nt][sig], acc[mt][nt][sig], 0, 0, 0);
#pragma unroll
        for (int mt = 0; mt < 3; ++mt) aCur[mt] = aNxt[mt];
    }

    // epilogue: C/D layout col = lane&15, row = (lane>>4)*4 + reg
    // out1 = C(mm); out0 = C(x) - C(mm)
    int tw = t0 + ng * 32 + lr;
#pragma unroll
    for (int mt = 0; mt < 3; ++mt) {
        int o0 = mg * 48 + mt * 16 + lk * 4;
#pragma unroll
        for (int nt = 0; nt < 2; ++nt) {
#pragma unroll
            for (int r4 = 0; r4 < 4; ++r4) {
                size_t idx = xb + (size_t)(o0 + r4) * NC + tw + nt * 16;
                float vm = acc[mt][nt][1][r4];
                out1[idx] = vm;
                out0[idx] = acc[mt][nt][0][r4] - vm;
            }
        }
    }
}

extern "C" void kernel_launch(void* const* d_in, const int* in_sizes, int n_in,
                              void* d_out, int out_size, void* d_ws, size_t ws_size,
                              hipStream_t stream)
{
    const float* x      = (const float*)d_in[0];
    const float* conv_w = (const float*)d_in[1];
    const float* gate_w = (const float*)d_in[2];
    const float* gate_b = (const float*)d_in[3];

    float* out0 = (float*)d_out;
    float* out1 = out0 + (size_t)NB * NL * NC;

    unsigned short* awb = (unsigned short*)d_ws;   // [96][288] bf16

    prep_aw<<<dim3((NL * KTOT + 255) / 256), 256, 0, stream>>>(conv_w, awb);
    fused_kernel<<<dim3(NB, NC / TT), 256, 0, stream>>>(x, gate_w, gate_b, awb, out0, out1);
}